// Round 1
// 338.358 us; speedup vs baseline: 1.0271x; 1.0271x over previous
//
#include <hip/hip_runtime.h>
#include <hip/hip_bf16.h>

// RowAttention, MFMA version (bf16 MFMA, fp32 acc). Inputs fp32, output fp32.
// One block per (b,h) row: grid=1024, block=512 (8 waves), 1 block/CU (LDS 156.5 KB).
//
// v2 (latency-bound fix):
//  - prep_weights kernel pre-converts wq/wk/wv to bf16 in d_ws, already in the
//    padded [64][72] chunk layout the MFMA frag reads want (conflict-free rows).
//  - weight staging is now global_load_lds (16B DMA) into a 36 KB 4-slot page
//    region, issued ahead (kc0/kc1 before P0; kc2/kc3 under P1 MFMAs; each wv
//    mc-chunk under the previous mc's O-GEMM), gated by counted vmcnt + raw
//    s_barrier. P1: 8 -> 4 barriers. P4: 44 -> 8 barriers.
//  - P0: all 16 x float4 loads prefetched at entry (one burst); transpose via
//    double-buffered [32][136+pad] fp32 scratch overlaid on the (dead) Qt/Kt
//    region, group-pad addressing SCW(c,w)=c*136+(c>>3)*8+w -> <=2 lanes/bank
//    on reads and writes. 32 barriers -> 9.
//
// LDS map (bytes):
//   [0,     67584)  Xt  [128 w][264 c] bf16                       (whole kernel)
//   [67584,104448)  P0 scratch dbuf (2x17472 fp32)  ->  Qt[128][72]+Kt[128][72]
//                   after P1  ->  Pl [128][136] bf16 after P2
//   [104448,141312) W pages: 4 slots x 9216 (P1: kc-pair = 2 slots; P4: wv kc)
//   [141312,158720) Vl  [64 c][136 v] bf16
//   [158720,160256) biases fp32: bq[64] bk[64] bv[256]

typedef short bf16x8 __attribute__((ext_vector_type(8)));
typedef float f32x4 __attribute__((ext_vector_type(4)));
using u32 = unsigned int;
using u16 = unsigned short;

#define XT_OFF   0
#define XT_SB    528
#define SA_OFF   67584
#define SB_OFF   85056
#define QT_OFF   67584
#define KT_OFF   86016
#define QK_SB    144
#define PL_OFF   67584
#define PL_SB    272
#define WP_OFF   104448
#define VL_OFF   141312
#define VL_SB    272
#define BIAS_OFF 158720
#define LDS_TOTAL 160256

// workspace: wqk_p [4 kc][2 sel(wq,wk)][64][72] bf16 (73728 B) then
//            wv_p  [4 mc][4 kc][64][72] bf16 (147456 B)
#define WS_WQK   0
#define WS_WV    73728

__device__ __forceinline__ u16 bfbits(float f) {
    __hip_bfloat16 h = __float2bfloat16(f);
    u16 u; __builtin_memcpy(&u, &h, 2); return u;
}
__device__ __forceinline__ u32 packbf2(float a, float b) {
    return (u32)bfbits(a) | ((u32)bfbits(b) << 16);
}
__device__ __forceinline__ float bf2f(u16 u) {
    union { u32 i; float f; } v; v.i = ((u32)u) << 16; return v.f;
}

// async global->LDS 16B copy; LDS dest must be wave-uniform (HW adds lane*16).
__device__ __forceinline__ void gl2lds16(const char* g, const char* l) {
    __builtin_amdgcn_global_load_lds(
        (const __attribute__((address_space(1))) void*)(unsigned long long)g,
        (__attribute__((address_space(3))) void*)(u32)(unsigned long long)l,
        16, 0, 0);
}
// stage 18432 B (one wq+wk chunk pair): per wave 2x1024 + 256  => 3 vm instrs
__device__ __forceinline__ void stage18k(const char* g, const char* lds, int w, int l) {
    gl2lds16(g + w * 1024 + l * 16,        lds + w * 1024);
    gl2lds16(g + 8192 + w * 1024 + l * 16, lds + 8192 + w * 1024);
    if (l < 16) gl2lds16(g + 16384 + w * 256 + l * 16, lds + 16384 + w * 256);
}
// stage 36864 B (4 wv chunks): per wave 4x1024 + 512  => 5 vm instrs
__device__ __forceinline__ void stage36k(const char* g, const char* lds, int w, int l) {
#pragma unroll
    for (int r = 0; r < 4; ++r)
        gl2lds16(g + r * 8192 + w * 1024 + l * 16, lds + r * 8192 + w * 1024);
    if (l < 32) gl2lds16(g + 32768 + w * 512 + l * 16, lds + 32768 + w * 512);
}

// raw barrier: no vmcnt drain (keeps DMA in flight); fenced against compiler motion
__device__ __forceinline__ void hard_barrier() {
    __builtin_amdgcn_sched_barrier(0);
    asm volatile("s_barrier" ::: "memory");
    __builtin_amdgcn_sched_barrier(0);
}

__global__ void prep_weights(const float* __restrict__ wq, const float* __restrict__ wk,
                             const float* __restrict__ wv, u32* __restrict__ ws) {
    int i = blockIdx.x * 256 + threadIdx.x;        // u32 word index, 55296 total
    if (i >= 55296) return;
    u32 v = 0;
    if (i < 18432) {                               // wqk_p: 8 chunk-halves of 2304 words
        int c = i / 2304, rem = i % 2304;
        int row = rem / 36, iw = rem % 36;
        int kc = c >> 1;
        const float* m = (c & 1) ? wk : wq;
        if (iw < 32) {
            int col = kc * 64 + iw * 2;
            v = packbf2(m[row * 256 + col], m[row * 256 + col + 1]);
        }
    } else {                                       // wv_p: 16 chunks of 2304 words
        int j = i - 18432;
        int c = j / 2304, rem = j % 2304;
        int row = rem / 36, iw = rem % 36;
        int mc = c >> 2, kc = c & 3;
        if (iw < 32) {
            int col = kc * 64 + iw * 2;
            v = packbf2(wv[(mc * 64 + row) * 256 + col], wv[(mc * 64 + row) * 256 + col + 1]);
        }
    }
    ws[i] = v;
}

__global__ __launch_bounds__(512, 1) void rowattn_mfma(
    const float* __restrict__ x,      // (8,256,128,128)
    const float* __restrict__ bq,     // (64,)
    const float* __restrict__ bk,     // (64,)
    const float* __restrict__ bv,     // (256,)
    const float* __restrict__ gamma,  // (1,)
    const char* __restrict__ wsp,     // prep_weights output (bf16, padded chunks)
    float* __restrict__ out)          // (8,256,128,128)
{
    __shared__ __align__(16) char smem[LDS_TOTAL];
    const int t  = threadIdx.x;
    const int bh = blockIdx.x;
    const int b  = bh >> 7;
    const int h  = bh & 127;
    const int l  = t & 63;
    const int a  = l & 15;                                  // MFMA col-within-tile
    const int q  = l >> 4;                                  // MFMA quad
    const int nw = __builtin_amdgcn_readfirstlane(t >> 6);  // wave id 0..7 = n-strip

    const char* wqk_g = wsp + WS_WQK;
    const char* wv_g  = wsp + WS_WV;
    const float g = gamma[0];

    // ---- early issues: W chunk-pairs kc=0,1 via DMA; biases; full x-row burst ----
    stage18k(wqk_g,         smem + WP_OFF,         nw, l);
    stage18k(wqk_g + 18432, smem + WP_OFF + 18432, nw, l);

    float* biasl = (float*)(smem + BIAS_OFF);
    if (t < 384) {
        float v;
        if (t < 64) v = bq[t];
        else if (t < 128) v = bk[t - 64];
        else v = bv[t - 128];
        biasl[t] = v;
    }

    const int cl = t >> 5;                                  // 0..15
    const int w4 = (t & 31) * 4;
    const float* xb = x + ((b * 256 + cl) * 128 + h) * 128 + w4;
    float4 xr[16];                                          // static idx (unrolled)
#pragma unroll
    for (int p = 0; p < 8; ++p) {
        xr[2 * p]     = *(const float4*)(xb + (p * 32) * 16384);
        xr[2 * p + 1] = *(const float4*)(xb + (p * 32 + 16) * 16384);
    }

    // ---- P0: stage x[b,:,h,:] transposed -> Xt[w][c] bf16 (dbuf scratch) ----
    // SCW group-pad: float4 writes 4-aligned; transpose reads <=2 lanes/bank.
    const int wrd = t >> 2;                                 // 0..127
    const int c8  = (t & 3) * 8;
#define SCW(c, w) ((c) * 136 + ((c) >> 3) * 8 + (w))
    {
        float* s0 = (float*)(smem + SA_OFF);
        *(float4*)&s0[SCW(cl, w4)]      = xr[0];
        *(float4*)&s0[SCW(cl + 16, w4)] = xr[1];
    }
    __syncthreads();
#pragma unroll
    for (int p = 0; p < 8; ++p) {
        float* sp = (float*)(smem + ((p & 1) ? SB_OFF : SA_OFF));
        if (p < 7) {                                        // stage next pass, other buffer
            float* sn = (float*)(smem + ((p & 1) ? SA_OFF : SB_OFF));
            *(float4*)&sn[SCW(cl, w4)]      = xr[2 * p + 2];
            *(float4*)&sn[SCW(cl + 16, w4)] = xr[2 * p + 3];
        }
        const float* sr = sp + SCW(c8, wrd);                // (c8+r)>>3 == c8>>3
        float s0 = sr[0],       s1 = sr[136],     s2 = sr[2 * 136], s3 = sr[3 * 136];
        float s4 = sr[4 * 136], s5 = sr[5 * 136], s6 = sr[6 * 136], s7 = sr[7 * 136];
        uint4 pk;
        pk.x = packbf2(s0, s1); pk.y = packbf2(s2, s3);
        pk.z = packbf2(s4, s5); pk.w = packbf2(s6, s7);
        *(uint4*)(smem + XT_OFF + wrd * XT_SB + (p * 32 + c8) * 2) = pk;
        __syncthreads();
    }
#undef SCW

    // ---- P1: Q,K projections -> Qt[wq][o], Kt[wk][o] bf16 (weights from pages) ----
    {
        f32x4 accQ[4], accK[4];
#pragma unroll
        for (int mt = 0; mt < 4; ++mt) {
            f32x4 cq, ck;
#pragma unroll
            for (int r = 0; r < 4; ++r) {
                cq[r] = biasl[mt * 16 + q * 4 + r];
                ck[r] = biasl[64 + mt * 16 + q * 4 + r];
            }
            accQ[mt] = cq; accK[mt] = ck;
        }
#pragma unroll
        for (int kc = 0; kc < 4; ++kc) {
            if (kc == 2) {  // my kc2 stage done (kc3's 3 instrs may stay in flight)
                asm volatile("s_waitcnt vmcnt(3)" ::: "memory");
                hard_barrier();
            }
            if (kc == 3) __syncthreads();                   // drains kc3 stage (vmcnt 0)
            const char* wqp = smem + WP_OFF + (kc & 1) * 18432;
            const char* wkp = wqp + 9216;
#pragma unroll
            for (int ks = 0; ks < 2; ++ks) {
                bf16x8 bx = *(const bf16x8*)(smem + XT_OFF + (nw * 16 + a) * XT_SB + (kc * 64 + ks * 32) * 2 + q * 16);
#pragma unroll
                for (int mt = 0; mt < 4; ++mt) {
                    bf16x8 aq = *(const bf16x8*)(wqp + (mt * 16 + a) * 144 + ks * 64 + q * 16);
                    accQ[mt] = __builtin_amdgcn_mfma_f32_16x16x32_bf16(aq, bx, accQ[mt], 0, 0, 0);
                    bf16x8 ak = *(const bf16x8*)(wkp + (mt * 16 + a) * 144 + ks * 64 + q * 16);
                    accK[mt] = __builtin_amdgcn_mfma_f32_16x16x32_bf16(ak, bx, accK[mt], 0, 0, 0);
                }
            }
            if (kc == 0) { __syncthreads(); stage18k(wqk_g + 2 * 18432, smem + WP_OFF,         nw, l); }
            if (kc == 1) { __syncthreads(); stage18k(wqk_g + 3 * 18432, smem + WP_OFF + 18432, nw, l); }
        }
        // write Qt/Kt transposed: C[m=o][n=w] -> Qt[w][o]
#pragma unroll
        for (int mt = 0; mt < 4; ++mt) {
            uint2 pq; pq.x = packbf2(accQ[mt][0], accQ[mt][1]); pq.y = packbf2(accQ[mt][2], accQ[mt][3]);
            *(uint2*)(smem + QT_OFF + (nw * 16 + a) * QK_SB + (mt * 16 + q * 4) * 2) = pq;
            uint2 pk; pk.x = packbf2(accK[mt][0], accK[mt][1]); pk.y = packbf2(accK[mt][2], accK[mt][3]);
            *(uint2*)(smem + KT_OFF + (nw * 16 + a) * QK_SB + (mt * 16 + q * 4) * 2) = pk;
        }
    }
    __syncthreads();

    // ---- P2: St[wk][wq], wave owns wq-strip nw (+ issue wv mc=0 stage under it) ----
    stage36k(wv_g, smem + WP_OFF, nw, l);
    f32x4 st[8];
#pragma unroll
    for (int mt = 0; mt < 8; ++mt) st[mt] = (f32x4){0.f, 0.f, 0.f, 0.f};
#pragma unroll
    for (int ks = 0; ks < 2; ++ks) {
        bf16x8 bqf = *(const bf16x8*)(smem + QT_OFF + (nw * 16 + a) * QK_SB + ks * 64 + q * 16);
#pragma unroll
        for (int mt = 0; mt < 8; ++mt) {
            bf16x8 akf = *(const bf16x8*)(smem + KT_OFF + (mt * 16 + a) * QK_SB + ks * 64 + q * 16);
            st[mt] = __builtin_amdgcn_mfma_f32_16x16x32_bf16(akf, bqf, st[mt], 0, 0, 0);
        }
    }
    // ---- P3: softmax over wk (in-lane + quad shuffles) ----
    {
        float mx = -3.0e38f;
#pragma unroll
        for (int mt = 0; mt < 8; ++mt)
#pragma unroll
            for (int r = 0; r < 4; ++r) mx = fmaxf(mx, st[mt][r]);
        mx = fmaxf(mx, __shfl_xor(mx, 16, 64));
        mx = fmaxf(mx, __shfl_xor(mx, 32, 64));
        float sum = 0.f;
#pragma unroll
        for (int mt = 0; mt < 8; ++mt)
#pragma unroll
            for (int r = 0; r < 4; ++r) { float e = __expf(st[mt][r] - mx); st[mt][r] = e; sum += e; }
        sum += __shfl_xor(sum, 16, 64);
        sum += __shfl_xor(sum, 32, 64);
        float inv = 1.0f / sum;
        hard_barrier();   // Qt/Kt frag reads done before Pl overlay (no vm drain: wv DMA in flight)
#pragma unroll
        for (int mt = 0; mt < 8; ++mt) {
            uint2 pp; pp.x = packbf2(st[mt][0] * inv, st[mt][1] * inv);
            pp.y = packbf2(st[mt][2] * inv, st[mt][3] * inv);
            *(uint2*)(smem + PL_OFF + (nw * 16 + a) * PL_SB + (mt * 16 + q * 4) * 2) = pp;
        }
        // Pl-ready barrier == P4 mc-loop top __syncthreads (drains wv DMA too)
    }

    // ---- P4: per 64-channel chunk: V = Wv.X + bv; O = V.P^T; out = g*O + x ----
#pragma unroll 1
    for (int mc = 0; mc < 4; ++mc) {
        __syncthreads();                                    // wv chunks + Pl ready; prev stores drained
        f32x4 accV[4];
#pragma unroll
        for (int mt = 0; mt < 4; ++mt) {
            f32x4 cv;
#pragma unroll
            for (int r = 0; r < 4; ++r) cv[r] = biasl[128 + mc * 64 + mt * 16 + q * 4 + r];
            accV[mt] = cv;
        }
#pragma unroll
        for (int kc = 0; kc < 4; ++kc) {
            const char* wvp = smem + WP_OFF + kc * 9216;
#pragma unroll
            for (int ks = 0; ks < 2; ++ks) {
                bf16x8 bx = *(const bf16x8*)(smem + XT_OFF + (nw * 16 + a) * XT_SB + (kc * 64 + ks * 32) * 2 + q * 16);
#pragma unroll
                for (int mt = 0; mt < 4; ++mt) {
                    bf16x8 av = *(const bf16x8*)(wvp + (mt * 16 + a) * 144 + ks * 64 + q * 16);
                    accV[mt] = __builtin_amdgcn_mfma_f32_16x16x32_bf16(av, bx, accV[mt], 0, 0, 0);
                }
            }
        }
        // write Vl[c][v]
#pragma unroll
        for (int mt = 0; mt < 4; ++mt)
#pragma unroll
            for (int r = 0; r < 4; ++r)
                *(u16*)(smem + VL_OFF + (mt * 16 + q * 4 + r) * VL_SB + (nw * 16 + a) * 2) = bfbits(accV[mt][r]);
        __syncthreads();                                    // Vl ready; all page reads done
        if (mc < 3) stage36k(wv_g + (mc + 1) * 36864, smem + WP_OFF, nw, l);  // hide under O-GEMM
        // O-GEMM: A=Vl[c][v], B=Pl[w][v]
        f32x4 accO[4];
#pragma unroll
        for (int mt = 0; mt < 4; ++mt) accO[mt] = (f32x4){0.f, 0.f, 0.f, 0.f};
#pragma unroll
        for (int ks = 0; ks < 4; ++ks) {
            bf16x8 bp = *(const bf16x8*)(smem + PL_OFF + (nw * 16 + a) * PL_SB + ks * 64 + q * 16);
#pragma unroll
            for (int mt = 0; mt < 4; ++mt) {
                bf16x8 av = *(const bf16x8*)(smem + VL_OFF + (mt * 16 + a) * VL_SB + ks * 64 + q * 16);
                accO[mt] = __builtin_amdgcn_mfma_f32_16x16x32_bf16(av, bp, accO[mt], 0, 0, 0);
            }
        }
        // epilogue: out = g*O + x (residual from bf16 Xt)
#pragma unroll
        for (int mt = 0; mt < 4; ++mt) {
#pragma unroll
            for (int r = 0; r < 4; ++r) {
                int c = mc * 64 + mt * 16 + q * 4 + r;
                int w = nw * 16 + a;
                u16 xv = *(const u16*)(smem + XT_OFF + w * XT_SB + c * 2);
                out[((b * 256 + c) * 128 + h) * 128 + w] = g * accO[mt][r] + bf2f(xv);
            }
        }
    }
}

extern "C" void kernel_launch(void* const* d_in, const int* in_sizes, int n_in,
                              void* d_out, int out_size, void* d_ws, size_t ws_size,
                              hipStream_t stream) {
    const float* x     = (const float*)d_in[0];
    const float* wq    = (const float*)d_in[1];
    const float* bq    = (const float*)d_in[2];
    const float* wk    = (const float*)d_in[3];
    const float* bk    = (const float*)d_in[4];
    const float* wv    = (const float*)d_in[5];
    const float* bv    = (const float*)d_in[6];
    const float* gamma = (const float*)d_in[7];
    float* out = (float*)d_out;

    hipLaunchKernelGGL(prep_weights, dim3(216), dim3(256), 0, stream, wq, wk, wv, (u32*)d_ws);
    hipLaunchKernelGGL(rowattn_mfma, dim3(1024), dim3(512), 0, stream,
                       x, bq, bk, bv, gamma, (const char*)d_ws, out);
}

// Round 2
// 295.519 us; speedup vs baseline: 1.1760x; 1.1450x over previous
//
#include <hip/hip_runtime.h>
#include <hip/hip_bf16.h>

// RowAttention, MFMA version (bf16 MFMA, fp32 acc). Inputs fp32, output fp32.
// One block per (b,h) row: grid=1024, block=1024 (16 waves), 1 block/CU.
//
// v3 (occupancy + write-coalescing fix):
//  - 16 waves (4/SIMD) instead of 8 (2/SIMD): doubles latency hiding.
//    Wave grid 4x4: mi = wid>>2 owns a 16-row m-slice, nj = wid&3 owns a
//    32-wide w-window (two adjacent 16-col n-tiles).
//  - Epilogue: each wave stores both 64B halves of every 128B out-line
//    back-to-back -> L2 write-coalescing restored (v2 split lines across
//    waves; WRITE_SIZE doubled to 262 MB + fetch-for-partial-write).
//  - Softmax: wk-dim now split across the 4 mi-waves -> two-level reduce:
//    in-wave (in-lane + q-shuffles) partial {max,sum}, then 4-way combine
//    via a 4 KB LDS partials buffer (overlaid on dead Vl region).
//  - P0 inner barriers are lgkm-only (no vmcnt drain): the 8-deep x float4
//    burst stays in flight across transpose passes.
//
// LDS map (bytes) - unchanged from v2:
//   [0,     67584)  Xt  [128 w][264 c] bf16                       (whole kernel)
//   [67584,104448)  P0 scratch dbuf (2x17472 fp32)  ->  Qt[128][72]+Kt[128][72]
//                   after P1  ->  Pl [128][136] bf16 after P2
//   [104448,141312) W pages: 4 slots x 9216 (P1: kc-pair = 2 slots; P4: wv kc)
//   [141312,158720) Vl  [64 c][136 v] bf16   (first 4 KB = softmax partials,
//                                             dead before first Vl write)
//   [158720,160256) biases fp32: bq[64] bk[64] bv[256]

typedef short bf16x8 __attribute__((ext_vector_type(8)));
typedef float f32x4 __attribute__((ext_vector_type(4)));
using u32 = unsigned int;
using u16 = unsigned short;

#define XT_OFF   0
#define XT_SB    528
#define SA_OFF   67584
#define SB_OFF   85056
#define QT_OFF   67584
#define KT_OFF   86016
#define QK_SB    144
#define PL_OFF   67584
#define PL_SB    272
#define WP_OFF   104448
#define VL_OFF   141312
#define VL_SB    272
#define SMP_OFF  141312
#define BIAS_OFF 158720
#define LDS_TOTAL 160256

// workspace: wqk_p [4 kc][2 sel(wq,wk)][64][72] bf16 (73728 B) then
//            wv_p  [4 mc][4 kc][64][72] bf16 (147456 B)
#define WS_WQK   0
#define WS_WV    73728

__device__ __forceinline__ u16 bfbits(float f) {
    __hip_bfloat16 h = __float2bfloat16(f);
    u16 u; __builtin_memcpy(&u, &h, 2); return u;
}
__device__ __forceinline__ u32 packbf2(float a, float b) {
    return (u32)bfbits(a) | ((u32)bfbits(b) << 16);
}
__device__ __forceinline__ float bf2f(u16 u) {
    union { u32 i; float f; } v; v.i = ((u32)u) << 16; return v.f;
}

// async global->LDS 16B copy; LDS dest is wave-uniform base + lane*16.
__device__ __forceinline__ void gl2lds16(const char* g, const char* l) {
    __builtin_amdgcn_global_load_lds(
        (const __attribute__((address_space(1))) void*)(unsigned long long)g,
        (__attribute__((address_space(3))) void*)(u32)(unsigned long long)l,
        16, 0, 0);
}
// stage 18432 B over 16 waves: uniform 2 vm instrs per wave
__device__ __forceinline__ void stage18k(const char* g, const char* lds, int w, int l) {
    gl2lds16(g + w * 1024 + l * 16, lds + w * 1024);
    if (l < 8) gl2lds16(g + 16384 + w * 128 + l * 16, lds + 16384 + w * 128);
}
// stage 36864 B over 16 waves: uniform 3 vm instrs per wave
__device__ __forceinline__ void stage36k(const char* g, const char* lds, int w, int l) {
    gl2lds16(g + w * 1024 + l * 16,         lds + w * 1024);
    gl2lds16(g + 16384 + w * 1024 + l * 16, lds + 16384 + w * 1024);
    if (l < 16) gl2lds16(g + 32768 + w * 256 + l * 16, lds + 32768 + w * 256);
}

// bare barrier: keeps DMA (vmcnt) AND prior-consumed LDS state; fenced
__device__ __forceinline__ void hard_barrier() {
    __builtin_amdgcn_sched_barrier(0);
    asm volatile("s_barrier" ::: "memory");
    __builtin_amdgcn_sched_barrier(0);
}
// LDS-visibility barrier: drains lgkmcnt only (ds_writes visible), vm stays in flight
__device__ __forceinline__ void lgkm_barrier() {
    __builtin_amdgcn_sched_barrier(0);
    asm volatile("s_waitcnt lgkmcnt(0)\n\ts_barrier" ::: "memory");
    __builtin_amdgcn_sched_barrier(0);
}

__global__ void prep_weights(const float* __restrict__ wq, const float* __restrict__ wk,
                             const float* __restrict__ wv, u32* __restrict__ ws) {
    int i = blockIdx.x * 256 + threadIdx.x;        // u32 word index, 55296 total
    if (i >= 55296) return;
    u32 v = 0;
    if (i < 18432) {                               // wqk_p: 8 chunk-halves of 2304 words
        int c = i / 2304, rem = i % 2304;
        int row = rem / 36, iw = rem % 36;
        int kc = c >> 1;
        const float* m = (c & 1) ? wk : wq;
        if (iw < 32) {
            int col = kc * 64 + iw * 2;
            v = packbf2(m[row * 256 + col], m[row * 256 + col + 1]);
        }
    } else {                                       // wv_p: 16 chunks of 2304 words
        int j = i - 18432;
        int c = j / 2304, rem = j % 2304;
        int row = rem / 36, iw = rem % 36;
        int mc = c >> 2, kc = c & 3;
        if (iw < 32) {
            int col = kc * 64 + iw * 2;
            v = packbf2(wv[(mc * 64 + row) * 256 + col], wv[(mc * 64 + row) * 256 + col + 1]);
        }
    }
    ws[i] = v;
}

__global__ __launch_bounds__(1024, 1) void rowattn_mfma(
    const float* __restrict__ x,      // (8,256,128,128)
    const float* __restrict__ bq,     // (64,)
    const float* __restrict__ bk,     // (64,)
    const float* __restrict__ bv,     // (256,)
    const float* __restrict__ gamma,  // (1,)
    const char* __restrict__ wsp,     // prep_weights output (bf16, padded chunks)
    float* __restrict__ out)          // (8,256,128,128)
{
    __shared__ __align__(16) char smem[LDS_TOTAL];
    const int t  = threadIdx.x;                             // 0..1023
    const int bh = blockIdx.x;
    const int b  = bh >> 7;
    const int h  = bh & 127;
    const int l  = t & 63;
    const int a  = l & 15;                                  // MFMA col-within-tile
    const int q  = l >> 4;                                  // MFMA quad
    const int wid = __builtin_amdgcn_readfirstlane(t >> 6); // 0..15
    const int mi = wid >> 2;                                // m-slice 0..3
    const int nj = wid & 3;                                 // n-window 0..3
    const int w0 = nj * 32;                                 // w-window base

    const char* wqk_g = wsp + WS_WQK;
    const char* wv_g  = wsp + WS_WV;
    const float g = gamma[0];

    // ---- early issues: W chunk-pairs kc=0,1 via DMA; biases; full x-row burst ----
    stage18k(wqk_g,         smem + WP_OFF,         wid, l);
    stage18k(wqk_g + 18432, smem + WP_OFF + 18432, wid, l);

    float* biasl = (float*)(smem + BIAS_OFF);
    if (t < 384) {
        float v;
        if (t < 64) v = bq[t];
        else if (t < 128) v = bk[t - 64];
        else v = bv[t - 128];
        biasl[t] = v;
    }

    const int cl = t >> 5;                                  // 0..31
    const int w4 = (t & 31) * 4;
    const float* xb = x + ((b * 256 + cl) * 128 + h) * 128 + w4;
    float4 xr[8];                                           // static idx (unrolled)
#pragma unroll
    for (int p = 0; p < 8; ++p) xr[p] = *(const float4*)(xb + (p * 32) * 16384);

    // ---- P0: stage x[b,:,h,:] transposed -> Xt[w][c] bf16 (dbuf scratch) ----
    // SCW group-pad: float4 writes uniform; transpose reads 2 lanes/bank (free).
    const int wrd = t >> 3;                                 // 0..127
    const int c4  = (t & 7) * 4;                            // 0,4,...,28
#define SCW(c, w) ((c) * 136 + ((c) >> 3) * 8 + (w))
    {
        float* s0 = (float*)(smem + SA_OFF);
        *(float4*)&s0[SCW(cl, w4)] = xr[0];
    }
    lgkm_barrier();
#pragma unroll
    for (int p = 0; p < 8; ++p) {
        float* sp = (float*)(smem + ((p & 1) ? SB_OFF : SA_OFF));
        if (p < 7) {                                        // stage next pass, other buffer
            float* sn = (float*)(smem + ((p & 1) ? SA_OFF : SB_OFF));
            *(float4*)&sn[SCW(cl, w4)] = xr[p + 1];
        }
        const float* sr = sp + SCW(c4, wrd);                // (c4+r)>>3 == c4>>3
        float s0 = sr[0], s1 = sr[136], s2 = sr[2 * 136], s3 = sr[3 * 136];
        uint2 pk; pk.x = packbf2(s0, s1); pk.y = packbf2(s2, s3);
        *(uint2*)(smem + XT_OFF + wrd * XT_SB + (p * 32 + c4) * 2) = pk;
        if (p < 7) lgkm_barrier();
    }
#undef SCW
    __syncthreads();    // drains vmcnt too: kc0/kc1 W pages + biases guaranteed

    // ---- P1: Q,K projections -> Qt[wq][o], Kt[wk][o] bf16 (weights from pages) ----
    {
        f32x4 accQ[2], accK[2];
#pragma unroll
        for (int nt = 0; nt < 2; ++nt) {
            f32x4 cq, ck;
#pragma unroll
            for (int r = 0; r < 4; ++r) {
                cq[r] = biasl[mi * 16 + q * 4 + r];
                ck[r] = biasl[64 + mi * 16 + q * 4 + r];
            }
            accQ[nt] = cq; accK[nt] = ck;
        }
#pragma unroll
        for (int kc = 0; kc < 4; ++kc) {
            if (kc == 2) {  // my kc2 stage (2 instrs) done; kc3's 2 may stay in flight
                asm volatile("s_waitcnt vmcnt(2)" ::: "memory");
                hard_barrier();
            }
            if (kc == 3) __syncthreads();                   // drains kc3 stage
            const char* wqp = smem + WP_OFF + (kc & 1) * 18432;
            const char* wkp = wqp + 9216;
#pragma unroll
            for (int ks = 0; ks < 2; ++ks) {
                bf16x8 aq = *(const bf16x8*)(wqp + (mi * 16 + a) * 144 + ks * 64 + q * 16);
                bf16x8 ak = *(const bf16x8*)(wkp + (mi * 16 + a) * 144 + ks * 64 + q * 16);
#pragma unroll
                for (int nt = 0; nt < 2; ++nt) {
                    bf16x8 bx = *(const bf16x8*)(smem + XT_OFF + (w0 + nt * 16 + a) * XT_SB + (kc * 64 + ks * 32) * 2 + q * 16);
                    accQ[nt] = __builtin_amdgcn_mfma_f32_16x16x32_bf16(aq, bx, accQ[nt], 0, 0, 0);
                    accK[nt] = __builtin_amdgcn_mfma_f32_16x16x32_bf16(ak, bx, accK[nt], 0, 0, 0);
                }
            }
            if (kc == 0) { hard_barrier(); stage18k(wqk_g + 2 * 18432, smem + WP_OFF,         wid, l); }
            if (kc == 1) { hard_barrier(); stage18k(wqk_g + 3 * 18432, smem + WP_OFF + 18432, wid, l); }
        }
        // write Qt/Kt transposed: C[m=o][n=w] -> Qt[w][o]
#pragma unroll
        for (int nt = 0; nt < 2; ++nt) {
            const int wrow = w0 + nt * 16 + a;
            uint2 pq; pq.x = packbf2(accQ[nt][0], accQ[nt][1]); pq.y = packbf2(accQ[nt][2], accQ[nt][3]);
            *(uint2*)(smem + QT_OFF + wrow * QK_SB + (mi * 16 + q * 4) * 2) = pq;
            uint2 pk; pk.x = packbf2(accK[nt][0], accK[nt][1]); pk.y = packbf2(accK[nt][2], accK[nt][3]);
            *(uint2*)(smem + KT_OFF + wrow * QK_SB + (mi * 16 + q * 4) * 2) = pk;
        }
    }
    __syncthreads();

    // ---- P2: St tiles; wave (mi,nj) owns wk in [mi*32,+32), wq in [nj*32,+32) ----
    stage36k(wv_g, smem + WP_OFF, wid, l);                  // wv mc=0, hidden under P2/P3
    f32x4 st[2][2];
#pragma unroll
    for (int mt2 = 0; mt2 < 2; ++mt2)
#pragma unroll
        for (int nt = 0; nt < 2; ++nt) st[mt2][nt] = (f32x4){0.f, 0.f, 0.f, 0.f};
#pragma unroll
    for (int ks = 0; ks < 2; ++ks) {
        bf16x8 bq0 = *(const bf16x8*)(smem + QT_OFF + (w0 + a) * QK_SB + ks * 64 + q * 16);
        bf16x8 bq1 = *(const bf16x8*)(smem + QT_OFF + (w0 + 16 + a) * QK_SB + ks * 64 + q * 16);
        bf16x8 ak0 = *(const bf16x8*)(smem + KT_OFF + (mi * 32 + a) * QK_SB + ks * 64 + q * 16);
        bf16x8 ak1 = *(const bf16x8*)(smem + KT_OFF + (mi * 32 + 16 + a) * QK_SB + ks * 64 + q * 16);
        st[0][0] = __builtin_amdgcn_mfma_f32_16x16x32_bf16(ak0, bq0, st[0][0], 0, 0, 0);
        st[0][1] = __builtin_amdgcn_mfma_f32_16x16x32_bf16(ak0, bq1, st[0][1], 0, 0, 0);
        st[1][0] = __builtin_amdgcn_mfma_f32_16x16x32_bf16(ak1, bq0, st[1][0], 0, 0, 0);
        st[1][1] = __builtin_amdgcn_mfma_f32_16x16x32_bf16(ak1, bq1, st[1][1], 0, 0, 0);
    }
    // ---- P3: softmax over wk: in-wave partial (32 wk) then 4-way mi-combine ----
    {
        float pmax[2], psum[2];
#pragma unroll
        for (int nt = 0; nt < 2; ++nt) {
            float mx = -3.0e38f;
#pragma unroll
            for (int mt2 = 0; mt2 < 2; ++mt2)
#pragma unroll
                for (int r = 0; r < 4; ++r) mx = fmaxf(mx, st[mt2][nt][r]);
            mx = fmaxf(mx, __shfl_xor(mx, 16, 64));
            mx = fmaxf(mx, __shfl_xor(mx, 32, 64));
            float s = 0.f;
#pragma unroll
            for (int mt2 = 0; mt2 < 2; ++mt2)
#pragma unroll
                for (int r = 0; r < 4; ++r) {
                    float e = __expf(st[mt2][nt][r] - mx); st[mt2][nt][r] = e; s += e;
                }
            s += __shfl_xor(s, 16, 64);
            s += __shfl_xor(s, 32, 64);
            pmax[nt] = mx; psum[nt] = s;
        }
        float2* smp = (float2*)(smem + SMP_OFF);            // [128 wq][4 mi]
        if (q == 0) {
#pragma unroll
            for (int nt = 0; nt < 2; ++nt)
                smp[(w0 + nt * 16 + a) * 4 + mi] = make_float2(pmax[nt], psum[nt]);
        }
        lgkm_barrier();                                     // partials visible; P2 reads done block-wide
        float f[2];
#pragma unroll
        for (int nt = 0; nt < 2; ++nt) {
            const int wq = w0 + nt * 16 + a;
            float2 p0 = smp[wq * 4 + 0], p1 = smp[wq * 4 + 1];
            float2 p2 = smp[wq * 4 + 2], p3 = smp[wq * 4 + 3];
            float m = fmaxf(fmaxf(p0.x, p1.x), fmaxf(p2.x, p3.x));
            float s = p0.y * __expf(p0.x - m) + p1.y * __expf(p1.x - m)
                    + p2.y * __expf(p2.x - m) + p3.y * __expf(p3.x - m);
            f[nt] = __expf(pmax[nt] - m) / s;
        }
        // Pl overlay of Qt/Kt is safe: barrier above was after all P2 reads
#pragma unroll
        for (int nt = 0; nt < 2; ++nt) {
            const int wq = w0 + nt * 16 + a;
#pragma unroll
            for (int mt2 = 0; mt2 < 2; ++mt2) {
                uint2 pp;
                pp.x = packbf2(st[mt2][nt][0] * f[nt], st[mt2][nt][1] * f[nt]);
                pp.y = packbf2(st[mt2][nt][2] * f[nt], st[mt2][nt][3] * f[nt]);
                *(uint2*)(smem + PL_OFF + wq * PL_SB + (mi * 32 + mt2 * 16 + q * 4) * 2) = pp;
            }
        }
        // Pl-ready barrier == P4 mc-loop top __syncthreads (drains wv DMA too)
    }

    // ---- P4: per 64-channel chunk: V = Wv.X + bv; O = V.P^T; out = g*O + x ----
#pragma unroll 1
    for (int mc = 0; mc < 4; ++mc) {
        __syncthreads();                                    // wv chunks + Pl ready; partials dead
        f32x4 accV[2];
        {
            f32x4 cv;
#pragma unroll
            for (int r = 0; r < 4; ++r) cv[r] = biasl[128 + mc * 64 + mi * 16 + q * 4 + r];
            accV[0] = cv; accV[1] = cv;
        }
#pragma unroll
        for (int kc = 0; kc < 4; ++kc) {
            const char* wvp = smem + WP_OFF + kc * 9216;
#pragma unroll
            for (int ks = 0; ks < 2; ++ks) {
                bf16x8 av = *(const bf16x8*)(wvp + (mi * 16 + a) * 144 + ks * 64 + q * 16);
#pragma unroll
                for (int nt = 0; nt < 2; ++nt) {
                    bf16x8 bx = *(const bf16x8*)(smem + XT_OFF + (w0 + nt * 16 + a) * XT_SB + (kc * 64 + ks * 32) * 2 + q * 16);
                    accV[nt] = __builtin_amdgcn_mfma_f32_16x16x32_bf16(av, bx, accV[nt], 0, 0, 0);
                }
            }
        }
        // write Vl[c][v]
#pragma unroll
        for (int nt = 0; nt < 2; ++nt)
#pragma unroll
            for (int r = 0; r < 4; ++r)
                *(u16*)(smem + VL_OFF + (mi * 16 + q * 4 + r) * VL_SB + (w0 + nt * 16 + a) * 2) = bfbits(accV[nt][r]);
        __syncthreads();                                    // Vl ready; all page reads done
        if (mc < 3) stage36k(wv_g + (mc + 1) * 36864, smem + WP_OFF, wid, l);  // hide under O-GEMM
        // O-GEMM: A=Vl[c][v], B=Pl[w][v]
        f32x4 accO[2];
        accO[0] = (f32x4){0.f, 0.f, 0.f, 0.f};
        accO[1] = (f32x4){0.f, 0.f, 0.f, 0.f};
#pragma unroll
        for (int ks = 0; ks < 4; ++ks) {
            bf16x8 av = *(const bf16x8*)(smem + VL_OFF + (mi * 16 + a) * VL_SB + ks * 64 + q * 16);
#pragma unroll
            for (int nt = 0; nt < 2; ++nt) {
                bf16x8 bp = *(const bf16x8*)(smem + PL_OFF + (w0 + nt * 16 + a) * PL_SB + ks * 64 + q * 16);
                accO[nt] = __builtin_amdgcn_mfma_f32_16x16x32_bf16(av, bp, accO[nt], 0, 0, 0);
            }
        }
        // epilogue: out = g*O + x; both 64B halves of each 128B line from THIS wave
#pragma unroll
        for (int r = 0; r < 4; ++r) {
            const int c = mc * 64 + mi * 16 + q * 4 + r;
            float* orow = out + ((b * 256 + c) * 128 + h) * 128;
#pragma unroll
            for (int nt = 0; nt < 2; ++nt) {
                const int w = w0 + nt * 16 + a;
                u16 xv = *(const u16*)(smem + XT_OFF + w * XT_SB + c * 2);
                orow[w] = g * accO[nt][r] + bf2f(xv);
            }
        }
    }
}

extern "C" void kernel_launch(void* const* d_in, const int* in_sizes, int n_in,
                              void* d_out, int out_size, void* d_ws, size_t ws_size,
                              hipStream_t stream) {
    const float* x     = (const float*)d_in[0];
    const float* wq    = (const float*)d_in[1];
    const float* bq    = (const float*)d_in[2];
    const float* wk    = (const float*)d_in[3];
    const float* bk    = (const float*)d_in[4];
    const float* wv    = (const float*)d_in[5];
    const float* bv    = (const float*)d_in[6];
    const float* gamma = (const float*)d_in[7];
    float* out = (float*)d_out;

    hipLaunchKernelGGL(prep_weights, dim3(216), dim3(256), 0, stream, wq, wk, wv, (u32*)d_ws);
    hipLaunchKernelGGL(rowattn_mfma, dim3(1024), dim3(1024), 0, stream,
                       x, bq, bk, bv, gamma, (const char*)d_ws, out);
}